// Round 7
// baseline (1825.844 us; speedup 1.0000x reference)
//
#include <hip/hip_runtime.h>

// CRF forward on MI355X — R5d: slim step (in-register Σ, folded normalizer).
// (Byte-equivalent to R5b/R5c — both died on container acquire with no
//  compile/pytest output. R4 hit the same infra flake once and its identical
//  resubmission passed. Third attempt; source re-audited for hang/fault
//  classes twice — none exist.)
//
// R4b measured 1648 cyc/step: matrix 620/CU, LDS ~1000/CU (reads 512 + sred
// machinery + conflicts), VALU ~833/SIMD (epilogue + sred round trip). R5 keeps
// the proven 16-batch dense-column MFMA structure and slims the two fat pipes:
//  - Sigma computed IN-STEP from the b-fragments each lane already holds
//    (31 v_pk_add_f16 + 2 shfl_xor) -> sred array, its LDS traffic, the 1-step
//    deferral, and its serial write->barrier->read chain all deleted. Exact:
//    any normalizer is exact as long as the SAME value is logged into Lam.
//  - g folded into the exponent: n = exp2(fma(y, log2e, -5 - log2 S)) * q
//    (kills rcp + 8 muls; v_exp_f32 is natively 2^x).
//  - cvt_pkrtz packed f32->f16 (4 insts / 8 values), 8 independent 2-deep
//    MFMA chains for shorter dependency tails.

typedef _Float16 f16x8 __attribute__((ext_vector_type(8)));
typedef _Float16 f16x2 __attribute__((ext_vector_type(2)));
typedef __fp16   fp16x2 __attribute__((ext_vector_type(2)));
typedef float    f32x4 __attribute__((ext_vector_type(4)));

#define TT 2048
#define KK 256
#define NB 16
#define NTH 512
#define SOS_IDX 2

#define MFMA(A, B, C) __builtin_amdgcn_mfma_f32_16x16x32_f16((A), (B), (C), 0, 0, 0)

static __device__ __forceinline__ float exp2_hw(float x) {
    float r; asm("v_exp_f32 %0, %1" : "=v"(r) : "v"(x)); return r;
}
static __device__ __forceinline__ unsigned pkrtz(float a, float b) {
    fp16x2 h = __builtin_amdgcn_cvt_pkrtz(a, b);
    return __builtin_bit_cast(unsigned, h);
}

__global__ __launch_bounds__(NTH, 2)
void crf_fwd_kernel(const float* __restrict__ y, const float* __restrict__ mask,
                    const float* __restrict__ trans, float* __restrict__ out)
{
    const int tid = threadIdx.x;
    const int w = tid >> 6, l = tid & 63;
    const int c = l & 15;            // column = batch-in-block (also A-row-in-tile)
    const int s = l >> 4;            // k-subgroup 0..3
    const int sw = (c & 7) << 4;     // LDS XOR swizzle (bits 4..6 of byte offset)
    const int bb = blockIdx.x * NB;

    __shared__ __align__(16) char  Vlds[2][NB * 512];   // [par][c][k] fp16, swizzled
    __shared__ float Lcs[NB];

    // ---- A fragments: af{0,1}[kt] = exp(trans)[32w + 16*rt + c][32kt + 8s + j]
    f16x8 af0[8], af1[8];
    {
        const float* t0 = trans + (size_t)(32 * w + c) * KK + 8 * s;
        const float* t1 = t0 + 16 * KK;
        #pragma unroll
        for (int kt = 0; kt < 8; ++kt) {
            float4 a0 = *(const float4*)(t0 + 32 * kt);
            float4 a1 = *(const float4*)(t0 + 32 * kt + 4);
            float4 b0 = *(const float4*)(t1 + 32 * kt);
            float4 b1 = *(const float4*)(t1 + 32 * kt + 4);
            f16x8 A, Bv;
            A[0] = (_Float16)__expf(a0.x); A[1] = (_Float16)__expf(a0.y);
            A[2] = (_Float16)__expf(a0.z); A[3] = (_Float16)__expf(a0.w);
            A[4] = (_Float16)__expf(a1.x); A[5] = (_Float16)__expf(a1.y);
            A[6] = (_Float16)__expf(a1.z); A[7] = (_Float16)__expf(a1.w);
            Bv[0] = (_Float16)__expf(b0.x); Bv[1] = (_Float16)__expf(b0.y);
            Bv[2] = (_Float16)__expf(b0.z); Bv[3] = (_Float16)__expf(b0.w);
            Bv[4] = (_Float16)__expf(b1.x); Bv[5] = (_Float16)__expf(b1.y);
            Bv[6] = (_Float16)__expf(b1.z); Bv[7] = (_Float16)__expf(b1.w);
            af0[kt] = A; af1[kt] = Bv;
        }
    }

    // ---- per-column lengths: 32 threads per batch row
    {
        const int cq = tid >> 5, q = tid & 31;
        const float* mrow = mask + (size_t)(bb + cq) * TT;
        float ls = 0.f;
        #pragma unroll
        for (int i = 0; i < TT / 32; ++i) ls += mrow[q + 32 * i];
        #pragma unroll
        for (int off = 16; off >= 1; off >>= 1) ls += __shfl_xor(ls, off, 64);
        if (q == 0) Lcs[cq] = ls;
    }

    // ---- init W (f32 regs, rows 32w+4s+{0..3} and +16, col c) = one-hot(SOS)
    const int r0 = 32 * w + 4 * s;
    float W0 = (r0 + 0 == SOS_IDX) ? 1.f : 0.f;
    float W1 = (r0 + 1 == SOS_IDX) ? 1.f : 0.f;
    float W2 = (r0 + 2 == SOS_IDX) ? 1.f : 0.f;
    float W3 = (r0 + 3 == SOS_IDX) ? 1.f : 0.f;
    float W4 = (r0 + 16 == SOS_IDX) ? 1.f : 0.f;
    float W5 = (r0 + 17 == SOS_IDX) ? 1.f : 0.f;
    float W6 = (r0 + 18 == SOS_IDX) ? 1.f : 0.f;
    float W7 = (r0 + 19 == SOS_IDX) ? 1.f : 0.f;
    {
        char* wb = Vlds[0] + (c << 9);
        *(uint2*)(wb + ((64 * w + 8 * s) ^ sw))      = make_uint2(pkrtz(W0, W1), pkrtz(W2, W3));
        *(uint2*)(wb + ((64 * w + 32 + 8 * s) ^ sw)) = make_uint2(pkrtz(W4, W5), pkrtz(W6, W7));
    }
    __syncthreads();

    float Tm = 0.f;
    #pragma unroll
    for (int i = 0; i < NB; ++i) Tm = fmaxf(Tm, Lcs[i]);
    const int Tmax = (int)(Tm + 0.5f);
    const int Lci  = (int)(Lcs[c] + 0.5f);

    // ---- y prefetch (2 ahead): lane owns (batch bb+c, rows r0..r0+3 and +16)
    const float* yb = y + (size_t)(bb + c) * (TT * KK) + 32 * w + 4 * s;
    float4 yA0 = *(const float4*)(yb);
    float4 yA1 = *(const float4*)(yb + 16);
    const int t1i = (Tmax > 1) ? 1 : 0;
    float4 yB0 = *(const float4*)(yb + (size_t)t1i * KK);
    float4 yB1 = *(const float4*)(yb + (size_t)t1i * KK + 16);
    float Lam = 0.f;

#define STEP(PAR, Y0, Y1, TS)                                                    \
  {                                                                              \
    const int t_ = (TS);                                                         \
    const char* vb = Vlds[PAR] + (c << 9);                                       \
    f16x8 b0 = *(const f16x8*)(vb + ((0   + (s << 4)) ^ sw));                    \
    f16x8 b1 = *(const f16x8*)(vb + ((64  + (s << 4)) ^ sw));                    \
    f16x8 b2 = *(const f16x8*)(vb + ((128 + (s << 4)) ^ sw));                    \
    f16x8 b3 = *(const f16x8*)(vb + ((192 + (s << 4)) ^ sw));                    \
    f16x8 b4 = *(const f16x8*)(vb + ((256 + (s << 4)) ^ sw));                    \
    f16x8 b5 = *(const f16x8*)(vb + ((320 + (s << 4)) ^ sw));                    \
    f16x8 b6 = *(const f16x8*)(vb + ((384 + (s << 4)) ^ sw));                    \
    f16x8 b7 = *(const f16x8*)(vb + ((448 + (s << 4)) ^ sw));                    \
    f16x8 ta = (b0 + b1) + (b2 + b3);                                            \
    f16x8 tb = (b4 + b5) + (b6 + b7);                                            \
    f16x8 tc = ta + tb;                                                          \
    f16x2 u0 = {tc[0], tc[1]}, u1 = {tc[2], tc[3]};                              \
    f16x2 u2 = {tc[4], tc[5]}, u3 = {tc[6], tc[7]};                              \
    f16x2 uu = (u0 + u1) + (u2 + u3);                                            \
    float Sl = (float)uu[0] + (float)uu[1];                                      \
    Sl += __shfl_xor(Sl, 16, 64);                                                \
    Sl += __shfl_xor(Sl, 32, 64);                                                \
    float lS  = __log2f(Sl);                                                     \
    float lgg = -5.0f - lS;                                                      \
    f32x4 zz = {0.f, 0.f, 0.f, 0.f};                                             \
    f32x4 c0a = zz, c0b = zz, c0c = zz, c0d = zz;                                \
    f32x4 c1a = zz, c1b = zz, c1c = zz, c1d = zz;                                \
    c0a = MFMA(af0[0], b0, c0a); c1a = MFMA(af1[0], b0, c1a);                    \
    c0b = MFMA(af0[2], b2, c0b); c1b = MFMA(af1[2], b2, c1b);                    \
    c0c = MFMA(af0[4], b4, c0c); c1c = MFMA(af1[4], b4, c1c);                    \
    c0d = MFMA(af0[6], b6, c0d); c1d = MFMA(af1[6], b6, c1d);                    \
    c0a = MFMA(af0[1], b1, c0a); c1a = MFMA(af1[1], b1, c1a);                    \
    c0b = MFMA(af0[3], b3, c0b); c1b = MFMA(af1[3], b3, c1b);                    \
    c0c = MFMA(af0[5], b5, c0c); c1c = MFMA(af1[5], b5, c1c);                    \
    c0d = MFMA(af0[7], b7, c0d); c1d = MFMA(af1[7], b7, c1d);                    \
    const bool on = (t_ < Lci);                                                  \
    f32x4 q0 = (c0a + c0b) + (c0c + c0d);                                        \
    f32x4 q1 = (c1a + c1b) + (c1c + c1d);                                        \
    float n0 = on ? exp2_hw(fmaf(Y0.x, 1.44269504f, lgg)) * q0[0] : W0;          \
    float n1 = on ? exp2_hw(fmaf(Y0.y, 1.44269504f, lgg)) * q0[1] : W1;          \
    float n2 = on ? exp2_hw(fmaf(Y0.z, 1.44269504f, lgg)) * q0[2] : W2;          \
    float n3 = on ? exp2_hw(fmaf(Y0.w, 1.44269504f, lgg)) * q0[3] : W3;          \
    float n4 = on ? exp2_hw(fmaf(Y1.x, 1.44269504f, lgg)) * q1[0] : W4;          \
    float n5 = on ? exp2_hw(fmaf(Y1.y, 1.44269504f, lgg)) * q1[1] : W5;          \
    float n6 = on ? exp2_hw(fmaf(Y1.z, 1.44269504f, lgg)) * q1[2] : W6;          \
    float n7 = on ? exp2_hw(fmaf(Y1.w, 1.44269504f, lgg)) * q1[3] : W7;          \
    W0 = n0; W1 = n1; W2 = n2; W3 = n3; W4 = n4; W5 = n5; W6 = n6; W7 = n7;      \
    Lam += on ? lS : 0.f;                                                        \
    char* wb = Vlds[(PAR) ^ 1] + (c << 9);                                       \
    *(uint2*)(wb + ((64 * w + 8 * s) ^ sw))      = make_uint2(pkrtz(n0, n1), pkrtz(n2, n3)); \
    *(uint2*)(wb + ((64 * w + 32 + 8 * s) ^ sw)) = make_uint2(pkrtz(n4, n5), pkrtz(n6, n7)); \
    { int tn = t_ + 2; if (tn > Tmax - 1) tn = Tmax - 1;                         \
      Y0 = *(const float4*)(yb + (size_t)tn * KK);                               \
      Y1 = *(const float4*)(yb + (size_t)tn * KK + 16); }                        \
    asm volatile("s_waitcnt lgkmcnt(0)" ::: "memory");                           \
    __builtin_amdgcn_s_barrier();                                                \
    __builtin_amdgcn_sched_barrier(0);                                           \
  }

    int t = 0;
    for (; t + 1 < Tmax; t += 2) {
        STEP(0, yA0, yA1, t);
        STEP(1, yB0, yB1, t + 1);
    }
    if (t < Tmax) STEP(0, yA0, yA1, t);

#undef STEP

    // ---- epilogue: Sigma over final V (wave 0; same in-register tree)
    if (w == 0) {
        const char* vb = Vlds[Tmax & 1] + (c << 9);
        f16x8 b0 = *(const f16x8*)(vb + ((0   + (s << 4)) ^ sw));
        f16x8 b1 = *(const f16x8*)(vb + ((64  + (s << 4)) ^ sw));
        f16x8 b2 = *(const f16x8*)(vb + ((128 + (s << 4)) ^ sw));
        f16x8 b3 = *(const f16x8*)(vb + ((192 + (s << 4)) ^ sw));
        f16x8 b4 = *(const f16x8*)(vb + ((256 + (s << 4)) ^ sw));
        f16x8 b5 = *(const f16x8*)(vb + ((320 + (s << 4)) ^ sw));
        f16x8 b6 = *(const f16x8*)(vb + ((384 + (s << 4)) ^ sw));
        f16x8 b7 = *(const f16x8*)(vb + ((448 + (s << 4)) ^ sw));
        f16x8 tc = ((b0 + b1) + (b2 + b3)) + ((b4 + b5) + (b6 + b7));
        f16x2 u0 = {tc[0], tc[1]}, u1 = {tc[2], tc[3]};
        f16x2 u2 = {tc[4], tc[5]}, u3 = {tc[6], tc[7]};
        f16x2 uu = (u0 + u1) + (u2 + u3);
        float Sf = (float)uu[0] + (float)uu[1];
        Sf += __shfl_xor(Sf, 16, 64);
        Sf += __shfl_xor(Sf, 32, 64);
        if (l < 16)
            out[bb + c] = 0.69314718056f * (Lam + __log2f(Sf) + 5.0f * (float)Lci);
    }
}

extern "C" void kernel_launch(void* const* d_in, const int* in_sizes, int n_in,
                              void* d_out, int out_size, void* d_ws, size_t ws_size,
                              hipStream_t stream) {
    const float* y     = (const float*)d_in[0];   // (B, T, K) fp32
    const float* mask  = (const float*)d_in[1];   // (B, T)    fp32
    const float* trans = (const float*)d_in[2];   // (K, K)    fp32
    float* out = (float*)d_out;                   // (B,)      fp32
    const int B = in_sizes[1] / TT;
    crf_fwd_kernel<<<B / NB, NTH, 0, stream>>>(y, mask, trans, out);
}